// Round 7
// baseline (361.529 us; speedup 1.0000x reference)
//
#include <hip/hip_runtime.h>

#define N_NODES 100000
#define N_EDGES 800000
#define FIN 64
#define HID 128
#define NB1 391   // ceil(N_NODES/256)
#define SRCS_CAP (N_EDGES + 7 * N_NODES)   // padded CSR capacity (pad to multiple of 8 per node)
#define BPS 3125  // node-chunks per slice (32 nodes/block, 3125*32 = 100000)
#define R1 (N_NODES + 1)                   // rows per slab incl. zero row

typedef unsigned short ushort_t;
typedef __attribute__((ext_vector_type(8))) short short8;   // 8 bf16 = 4 VGPRs (MFMA A/B frag)
typedef __attribute__((ext_vector_type(16))) float fx16;    // 32x32 MFMA C/D frag
typedef __attribute__((ext_vector_type(4))) unsigned short us4;
typedef __attribute__((ext_vector_type(4))) unsigned int u32x4;  // ext-vector for nontemporal st

__device__ inline ushort_t f2bf(float f) {   // RNE fp32 -> bf16
    unsigned u = __float_as_uint(f);
    u += 0x7fffu + ((u >> 16) & 1u);
    return (ushort_t)(u >> 16);
}
__device__ inline float bf2f(ushort_t h) { return __uint_as_float(((unsigned)h) << 16); }

__device__ inline void upadd(float* acc, uint4 A) {   // accumulate 8 bf16 of a 16B chunk
    acc[0] += __uint_as_float(A.x << 16);
    acc[1] += __uint_as_float(A.x & 0xffff0000u);
    acc[2] += __uint_as_float(A.y << 16);
    acc[3] += __uint_as_float(A.y & 0xffff0000u);
    acc[4] += __uint_as_float(A.z << 16);
    acc[5] += __uint_as_float(A.z & 0xffff0000u);
    acc[6] += __uint_as_float(A.w << 16);
    acc[7] += __uint_as_float(A.w & 0xffff0000u);
}

// ---------------- utility ----------------
// zero deg + flag, fill padded srcs with sentinel row N_NODES (zero row)
__global__ void zero_int_kernel(int* __restrict__ deg, int* __restrict__ flag,
                                int* __restrict__ srcs) {
    int i = blockIdx.x * 256 + threadIdx.x;
    if (i < N_NODES) deg[i] = 0;
    if (i == 0) *flag = 0;
    for (int k = i; k < SRCS_CAP; k += NB1 * 256) srcs[k] = N_NODES;
}

// int32 vs int64 edge_index layout probe (int64 little-endian => odd words all 0)
__global__ void detect_kernel(const int* __restrict__ w, int* __restrict__ flag) {
    int i = blockIdx.x * 256 + threadIdx.x;
    if (i < 8192) {
        if (w[2 * i + 1] != 0) atomicOr(flag, 1);
    }
}

// ---------------- CSR build (padded to multiple of 8 per node) ----------------
__global__ void hist_kernel(const int* __restrict__ w, const int* __restrict__ flag,
                            int* __restrict__ deg, int* __restrict__ rank) {
    int e = blockIdx.x * 256 + threadIdx.x;
    if (e >= N_EDGES) return;
    int is32 = *flag;
    int d = is32 ? w[N_EDGES + e] : w[2 * (N_EDGES + e)];
    rank[e] = atomicAdd(&deg[d], 1);
}

__global__ void scan1_kernel(const int* __restrict__ deg, int* __restrict__ off,
                             int* __restrict__ bsums) {
    __shared__ int s[256];
    int t = threadIdx.x;
    int i = blockIdx.x * 256 + t;
    int v = (i < N_NODES) ? ((deg[i] + 7) & ~7) : 0;   // padded degree
    s[t] = v;
    __syncthreads();
    for (int d = 1; d < 256; d <<= 1) {
        int w = (t >= d) ? s[t - d] : 0;
        __syncthreads();
        s[t] += w;
        __syncthreads();
    }
    if (i < N_NODES) off[i] = s[t] - v;
    if (t == 255) bsums[blockIdx.x] = s[255];
}

__global__ void scan2_kernel(int* __restrict__ bsums) {
    __shared__ int s[512];
    int t = threadIdx.x;
    int v = (t < NB1) ? bsums[t] : 0;
    s[t] = v;
    __syncthreads();
    for (int d = 1; d < 512; d <<= 1) {
        int w = (t >= d) ? s[t - d] : 0;
        __syncthreads();
        s[t] += w;
        __syncthreads();
    }
    if (t < NB1) bsums[t] = s[t] - v;
    if (t == NB1 - 1) bsums[NB1] = s[t];   // total padded edge count
}

__global__ void scan3_kernel(int* __restrict__ off, const int* __restrict__ bsums) {
    int i = blockIdx.x * 256 + threadIdx.x;
    if (i < N_NODES) off[i] = off[i] + bsums[blockIdx.x];
    if (i == 0) off[N_NODES] = bsums[NB1];
}

__global__ void scatter_kernel(const int* __restrict__ w, const int* __restrict__ flag,
                               const int* __restrict__ off, const int* __restrict__ rank,
                               int* __restrict__ srcs) {
    int e = blockIdx.x * 256 + threadIdx.x;
    if (e >= N_EDGES) return;
    int is32 = *flag;
    int s = is32 ? w[e] : w[2 * e];
    int d = is32 ? w[N_EDGES + e] : w[2 * (N_EDGES + e)];
    srcs[off[d] + rank[e]] = s;
}

// ---------------- dtype conversion + sentinel zero rows ----------------
// xs slice-major: 8 slabs x R1 rows x 16B (slab k = bytes [16k,16k+16) of each x row)
// Wb1[n][k], k<64 -> W1rel, else W1root. Wb2[n][k], k<128 -> W2rel, else W2root.
__global__ void cvt_kernel(const float* __restrict__ x, ushort_t* __restrict__ xs,
                           const float* __restrict__ W1rel, const float* __restrict__ W1root,
                           const float* __restrict__ W2rel, const float* __restrict__ W2root,
                           ushort_t* __restrict__ Wb1, ushort_t* __restrict__ Wb2,
                           ushort_t* __restrict__ h1s) {
    int i = blockIdx.x * 256 + threadIdx.x; // quad id for x
    if (i < N_NODES * FIN / 4) {
        float4 v = ((const float4*)x)[i];
        us4 o = {f2bf(v.x), f2bf(v.y), f2bf(v.z), f2bf(v.w)};
        int n = i >> 4;                 // node
        int slab = (i & 15) >> 1;       // 0..7 (16B slices of the 128B row)
        ((us4*)(xs + ((size_t)slab * R1 + n) * 8))[i & 1] = o;
    }
    us4 z = {0, 0, 0, 0};
    if (i < 16) {                       // xs zero rows: 8 slabs x 16B
        int slab = i >> 1;
        ((us4*)(xs + ((size_t)slab * R1 + N_NODES) * 8))[i & 1] = z;
    }
    if (i >= 16 && i < 48) {            // h1s zero rows: 8 slabs x 32B
        int t = i - 16;
        int slab = t >> 2;
        ((us4*)(h1s + ((size_t)slab * R1 + N_NODES) * 16))[t & 3] = z;
    }
    if (i < HID * HID) {
        int n = i >> 7, k = i & 127;
        float v = (k < FIN) ? W1rel[n * FIN + k] : W1root[n * FIN + (k - FIN)];
        Wb1[i] = f2bf(v);
    }
    if (i < HID * 2 * HID) {
        int n = i >> 8, k = i & 255;
        float v = (k < HID) ? W2rel[n * HID + k] : W2root[n * HID + (k - HID)];
        Wb2[i] = f2bf(v);
    }
}

// ------- aggregation: slice-major gather tables, slice pinned to XCD via blockIdx&7 -------
// Locality heuristic only (blockIdx%8 round-robins over XCDs); correctness slice-independent.
// agg1: xs slabs 1.6 MB; lane map 8 nodes x 8 edge slots x 16B. Output row-major agg1b.
__global__ void agg1_kernel(const ushort_t* __restrict__ xs, const int* __restrict__ off,
                            const int* __restrict__ srcs, ushort_t* __restrict__ aggb) {
    int slice = blockIdx.x & 7;
    int nblk = blockIdx.x >> 3;
    int wave = threadIdx.x >> 6;
    int lane = threadIdx.x & 63;
    int n = lane >> 3;                       // node sub 0..7
    unsigned g = lane & 7;                   // edge slot 0..7
    int node = nblk * 32 + wave * 8 + n;     // exact grid: always < N_NODES
    int b = off[node], e = off[node + 1];
    float acc[8];
#pragma unroll
    for (int j = 0; j < 8; j++) acc[j] = 0.f;
    const uint4* rows = (const uint4*)(xs + (size_t)slice * R1 * 8);  // 16B per row
    for (int p = b; p < e; p += 8) {
        unsigned s0 = (unsigned)__builtin_nontemporal_load(&srcs[p + g]);
        uint4 A = rows[s0];
        upadd(acc, A);
    }
#pragma unroll
    for (int j = 0; j < 8; j++) {            // reduce over 8 slots (lane bits 0..2)
        acc[j] += __shfl_xor(acc[j], 1);
        acc[j] += __shfl_xor(acc[j], 2);
        acc[j] += __shfl_xor(acc[j], 4);
    }
    if (g == 0) {                            // 8 lanes: one per node
        u32x4 o = {(unsigned)f2bf(acc[0]) | ((unsigned)f2bf(acc[1]) << 16),
                   (unsigned)f2bf(acc[2]) | ((unsigned)f2bf(acc[3]) << 16),
                   (unsigned)f2bf(acc[4]) | ((unsigned)f2bf(acc[5]) << 16),
                   (unsigned)f2bf(acc[6]) | ((unsigned)f2bf(acc[7]) << 16)};
        __builtin_nontemporal_store(o, (u32x4*)(aggb + (size_t)node * FIN + slice * 8));
    }
}

// agg2: h1s slabs 3.2 MB; lane map 8 nodes x 4 slots x 2 chunks (32B slice). Row-major agg2b.
__global__ void agg2_kernel(const ushort_t* __restrict__ h1s, const int* __restrict__ off,
                            const int* __restrict__ srcs, ushort_t* __restrict__ aggb) {
    int slice = blockIdx.x & 7;
    int nblk = blockIdx.x >> 3;
    int wave = threadIdx.x >> 6;
    int lane = threadIdx.x & 63;
    int n = lane >> 3;                       // node sub 0..7
    unsigned g = (lane >> 1) & 3;            // edge slot 0..3
    unsigned c = lane & 1;                   // 16B chunk of the 32B slice
    int node = nblk * 32 + wave * 8 + n;
    int b = off[node], e = off[node + 1];
    float acc[8];
#pragma unroll
    for (int j = 0; j < 8; j++) acc[j] = 0.f;
    const uint4* rows = (const uint4*)(h1s + (size_t)slice * R1 * 16);  // 32B per row
    for (int p = b; p < e; p += 4) {
        unsigned s0 = (unsigned)__builtin_nontemporal_load(&srcs[p + g]);
        uint4 A = rows[s0 * 2u + c];
        upadd(acc, A);
    }
#pragma unroll
    for (int j = 0; j < 8; j++) {            // reduce over 4 slots (lane bits 1,2)
        acc[j] += __shfl_xor(acc[j], 2);
        acc[j] += __shfl_xor(acc[j], 4);
    }
    if ((lane & 6) == 0) {                   // 16 lanes: 8 nodes x 2 chunks
        u32x4 o = {(unsigned)f2bf(acc[0]) | ((unsigned)f2bf(acc[1]) << 16),
                   (unsigned)f2bf(acc[2]) | ((unsigned)f2bf(acc[3]) << 16),
                   (unsigned)f2bf(acc[4]) | ((unsigned)f2bf(acc[5]) << 16),
                   (unsigned)f2bf(acc[6]) | ((unsigned)f2bf(acc[7]) << 16)};
        __builtin_nontemporal_store(o, (u32x4*)(aggb + (size_t)node * HID + slice * 16) + c);
    }
}

// ------- MFMA GEMM layer 1: h1 = elu([agg1,x] @ Wb1^T + b1), h1 written slice-major -------
__global__ __launch_bounds__(256) void g1_kernel(
    const ushort_t* __restrict__ aggb, const ushort_t* __restrict__ xs,
    const ushort_t* __restrict__ Wb1, const float* __restrict__ b1,
    ushort_t* __restrict__ h1s) {
    __shared__ short8 wl8[2048];                 // 32 KB
    ushort_t* wl = (ushort_t*)wl8;
#pragma unroll
    for (int it = 0; it < 8; it++) {
        int q = it * 256 + threadIdx.x;
        int n = q >> 4, c = q & 15;
        short8 v = ((const short8*)Wb1)[q];
        *(short8*)(wl + n * HID + ((c ^ (n & 7)) << 3)) = v;
    }
    __syncthreads();

    int wave = threadIdx.x >> 6;
    int lane = threadIdx.x & 63;
    int nb = blockIdx.x * 128 + wave * 32;
    if (nb >= N_NODES) return;   // after the only barrier
    int half = lane >> 5, col = lane & 31;
    int nA = nb + col;
    if (nA >= N_NODES) nA = N_NODES - 1;

    short8 areg[8];
#pragma unroll
    for (int s = 0; s < 4; s++)
        areg[s] = *(const short8*)(aggb + (size_t)nA * FIN + s * 16 + half * 8);
#pragma unroll
    for (int s = 4; s < 8; s++) {            // x own-row from slice-major xs
        int slab = (s - 4) * 2 + half;
        areg[s] = *(const short8*)(xs + ((size_t)slab * R1 + nA) * 8);
    }

    fx16 acc[4];
#pragma unroll
    for (int jt = 0; jt < 4; jt++)
#pragma unroll
        for (int r = 0; r < 16; r++) acc[jt][r] = 0.f;

#pragma unroll
    for (int s = 0; s < 8; s++) {
        int c = 2 * s + half;
#pragma unroll
        for (int jt = 0; jt < 4; jt++) {
            int n = jt * 32 + col;
            short8 bq = *(const short8*)(wl + n * HID + ((c ^ (n & 7)) << 3));
            acc[jt] = __builtin_amdgcn_mfma_f32_32x32x16_bf16(areg[s], bq, acc[jt], 0, 0, 0);
        }
    }
#pragma unroll
    for (int jt = 0; jt < 4; jt++) {
        int j = jt * 32 + col;
        float bias = b1[j];
        int slab = jt * 2 + (col >> 4);
        int jin = col & 15;
#pragma unroll
        for (int r = 0; r < 16; r++) {
            int node = nb + (r & 3) + 8 * (r >> 2) + 4 * half;
            if (node < N_NODES) {
                float v = acc[jt][r] + bias;
                v = v > 0.f ? v : __expf(v) - 1.f;
                h1s[((size_t)slab * R1 + node) * 16 + jin] = f2bf(v);
            }
        }
    }
}

// ------- MFMA GEMM layer 2 + MFMA MLP head (h1 read slice-major) -------
__global__ __launch_bounds__(256) void g2h_kernel(
    const ushort_t* __restrict__ agg2b, const ushort_t* __restrict__ h1s,
    const ushort_t* __restrict__ Wb2, const float* __restrict__ b2,
    const float* __restrict__ Wfc1, const float* __restrict__ bfc1,
    const float* __restrict__ Wfc2, const float* __restrict__ bfc2,
    float* __restrict__ out) {
    __shared__ ushort_t smem[21504];             // 43008 B
    ushort_t* wl = smem;                         // 16384 ushorts (32 KB)
    ushort_t* wf = smem + 17408;                 // 4096 ushorts (8 KB)

    // stage Wfc1b once (region never touched by Wb2/tile)
#pragma unroll
    for (int it = 0; it < 16; it++) {
        int idx = it * 256 + threadIdx.x;        // 0..4095
        int m = idx >> 7, k = idx & 127;
        float v = (m < 20) ? Wfc1[m * HID + k] : 0.f;
        wf[m * 128 + (((k >> 3) ^ (m & 7)) << 3) + (k & 7)] = f2bf(v);
    }
    // stage Wb2 K-half 0 (cols 0..127)
#pragma unroll
    for (int it = 0; it < 8; it++) {
        int q = it * 256 + threadIdx.x;          // 0..2047
        int n = q >> 4, c = q & 15;
        short8 v = *(const short8*)(Wb2 + (size_t)n * 256 + c * 8);
        *(short8*)(wl + n * 128 + ((c ^ (n & 7)) << 3)) = v;
    }

    int wave = threadIdx.x >> 6;
    int lane = threadIdx.x & 63;
    int half = lane >> 5, col = lane & 31;
    int nb = blockIdx.x * 128 + wave * 32;       // tail waves keep running (barriers!)
    int nA = nb + col;
    if (nA >= N_NODES) nA = N_NODES - 1;

    short8 areg[16];
#pragma unroll
    for (int s = 0; s < 8; s++)
        areg[s] = *(const short8*)(agg2b + (size_t)nA * HID + s * 16 + half * 8);
#pragma unroll
    for (int s = 8; s < 16; s++)             // h1 own-row from slice-major h1s
        areg[s] = *(const short8*)(h1s + ((size_t)(s - 8) * R1 + nA) * 16 + half * 8);

    fx16 acc[4];
#pragma unroll
    for (int jt = 0; jt < 4; jt++)
#pragma unroll
        for (int r = 0; r < 16; r++) acc[jt][r] = 0.f;

    __syncthreads();
#pragma unroll
    for (int s = 0; s < 8; s++) {                // K 0..127 (agg2 part)
        int c = 2 * s + half;
#pragma unroll
        for (int jt = 0; jt < 4; jt++) {
            int n = jt * 32 + col;
            short8 bq = *(const short8*)(wl + n * 128 + ((c ^ (n & 7)) << 3));
            acc[jt] = __builtin_amdgcn_mfma_f32_32x32x16_bf16(areg[s], bq, acc[jt], 0, 0, 0);
        }
    }
    __syncthreads();
    // stage Wb2 K-half 1 (cols 128..255)
#pragma unroll
    for (int it = 0; it < 8; it++) {
        int q = it * 256 + threadIdx.x;
        int n = q >> 4, c = q & 15;
        short8 v = *(const short8*)(Wb2 + (size_t)n * 256 + 128 + c * 8);
        *(short8*)(wl + n * 128 + ((c ^ (n & 7)) << 3)) = v;
    }
    __syncthreads();
#pragma unroll
    for (int s = 8; s < 16; s++) {               // K 128..255 (h1 part)
        int c = 2 * (s - 8) + half;
#pragma unroll
        for (int jt = 0; jt < 4; jt++) {
            int n = jt * 32 + col;
            short8 bq = *(const short8*)(wl + n * 128 + ((c ^ (n & 7)) << 3));
            acc[jt] = __builtin_amdgcn_mfma_f32_32x32x16_bf16(areg[s], bq, acc[jt], 0, 0, 0);
        }
    }
    __syncthreads();   // weights dead; reuse [0..34816) as t2 tile

    // t2 tile [node_local][feature], stride 136 ushorts
    ushort_t* tl = smem;
#pragma unroll
    for (int jt = 0; jt < 4; jt++) {
        int j = jt * 32 + col;
        float bias = b2[j];
#pragma unroll
        for (int r = 0; r < 16; r++) {
            int nl = wave * 32 + (r & 3) + 8 * (r >> 2) + 4 * half;
            tl[nl * 136 + j] = f2bf(acc[jt][r] + bias);
        }
    }
    __syncthreads();

    // fc1 as MFMA: A = t2 tile rows (node m = wave*32+col), B = Wfc1b (row col)
    short8 af[8];
#pragma unroll
    for (int s = 0; s < 8; s++)
        af[s] = *(const short8*)(tl + (wave * 32 + col) * 136 + s * 16 + half * 8);
    fx16 fa;
#pragma unroll
    for (int r = 0; r < 16; r++) fa[r] = 0.f;
#pragma unroll
    for (int s = 0; s < 8; s++) {
        int c = 2 * s + half;
        short8 bw = *(const short8*)(wf + col * 128 + ((c ^ (col & 7)) << 3));
        fa = __builtin_amdgcn_mfma_f32_32x32x16_bf16(af[s], bw, fa, 0, 0, 0);
    }
    // epilogue: relu(+bfc1) * Wfc2, butterfly-sum over the 32 output cols
    float biasv = (col < 20) ? bfc1[col] : 0.f;
    float w2v = (col < 20) ? Wfc2[col] : 0.f;
    float bz = bfc2[0];
    float red[16];
#pragma unroll
    for (int r = 0; r < 16; r++) {
        float v = fa[r] + biasv;
        v = (v > 0.f ? v : 0.f) * w2v;
        v += __shfl_xor(v, 1);
        v += __shfl_xor(v, 2);
        v += __shfl_xor(v, 4);
        v += __shfl_xor(v, 8);
        v += __shfl_xor(v, 16);
        red[r] = v;
    }
    if (col == 0) {
#pragma unroll
        for (int r = 0; r < 16; r++) {
            int nl = wave * 32 + (r & 3) + 8 * (r >> 2) + 4 * half;
            int ng = blockIdx.x * 128 + nl;
            if (ng < N_NODES) out[ng] = red[r] + bz;
        }
    }
}

// ---------------- launch ----------------
extern "C" void kernel_launch(void* const* d_in, const int* in_sizes, int n_in,
                              void* d_out, int out_size, void* d_ws, size_t ws_size,
                              hipStream_t stream) {
    const float* x = (const float*)d_in[0];
    const int* ei = (const int*)d_in[1];
    const float* W1rel = (const float*)d_in[2];
    const float* b1 = (const float*)d_in[3];
    const float* W1root = (const float*)d_in[4];
    const float* W2rel = (const float*)d_in[5];
    const float* b2 = (const float*)d_in[6];
    const float* W2root = (const float*)d_in[7];
    const float* Wfc1 = (const float*)d_in[8];
    const float* bfc1 = (const float*)d_in[9];
    const float* Wfc2 = (const float*)d_in[10];
    const float* bfc2 = (const float*)d_in[11];
    float* out = (float*)d_out;

    char* ws = (char*)d_ws;
    size_t o = 0;
    int* deg = (int*)(ws + o);       o += (size_t)N_NODES * 4;
    int* off = (int*)(ws + o);       o += (size_t)(N_NODES + 1) * 4 + 12;
    int* bsums = (int*)(ws + o);     o += 4096;
    int* flag = (int*)(ws + o);      o += 16;
    int* rank = (int*)(ws + o);      o += (size_t)N_EDGES * 4;                  // 3.2 MB
    int* srcs = (int*)(ws + o);      o += (size_t)SRCS_CAP * 4;                 // 6.0 MB
    ushort_t* xs = (ushort_t*)(ws + o);    o += (size_t)R1 * FIN * 2;             // 12.8 MB slice-major
    ushort_t* agg1b = (ushort_t*)(ws + o); o += (size_t)N_NODES * FIN * 2;        // 12.8 MB
    ushort_t* h1s = (ushort_t*)(ws + o);   o += (size_t)R1 * HID * 2;             // 25.6 MB slice-major
    ushort_t* agg2b = (ushort_t*)(ws + o); o += (size_t)N_NODES * HID * 2;        // 25.6 MB
    ushort_t* Wb1 = (ushort_t*)(ws + o);   o += (size_t)HID * HID * 2;            // 32 KB
    ushort_t* Wb2 = (ushort_t*)(ws + o);   o += (size_t)HID * 2 * HID * 2;        // 64 KB

    const int GW = (N_NODES + 127) / 128; // 782 blocks: 4 waves x 32 nodes
    const int GA = 8 * BPS;               // 25000 blocks: slice = blockIdx & 7

    zero_int_kernel<<<NB1, 256, 0, stream>>>(deg, flag, srcs);
    detect_kernel<<<32, 256, 0, stream>>>(ei, flag);
    hist_kernel<<<(N_EDGES + 255) / 256, 256, 0, stream>>>(ei, flag, deg, rank);
    scan1_kernel<<<NB1, 256, 0, stream>>>(deg, off, bsums);
    scan2_kernel<<<1, 512, 0, stream>>>(bsums);
    scan3_kernel<<<NB1, 256, 0, stream>>>(off, bsums);
    scatter_kernel<<<(N_EDGES + 255) / 256, 256, 0, stream>>>(ei, flag, off, rank, srcs);
    cvt_kernel<<<(N_NODES * FIN / 4 + 255) / 256, 256, 0, stream>>>(
        x, xs, W1rel, W1root, W2rel, W2root, Wb1, Wb2, h1s);
    agg1_kernel<<<GA, 256, 0, stream>>>(xs, off, srcs, agg1b);
    g1_kernel<<<GW, 256, 0, stream>>>(agg1b, xs, Wb1, b1, h1s);
    agg2_kernel<<<GA, 256, 0, stream>>>(h1s, off, srcs, agg2b);
    g2h_kernel<<<GW, 256, 0, stream>>>(agg2b, h1s, Wb2, b2, Wfc1, bfc1, Wfc2, bfc2, out);
}

// Round 10
// 251.876 us; speedup vs baseline: 1.4353x; 1.4353x over previous
//
#include <hip/hip_runtime.h>

#define N_NODES 100000
#define N_EDGES 800000
#define FIN 64
#define HID 128
#define NB1 391   // ceil(N_NODES/256)
#define SRCS_CAP (N_EDGES + 3 * N_NODES)   // padded CSR capacity (pad to multiple of 4 per node)

typedef unsigned short ushort_t;
typedef __attribute__((ext_vector_type(8))) short short8;   // 8 bf16 = 4 VGPRs (MFMA A/B frag)
typedef __attribute__((ext_vector_type(16))) float fx16;    // 32x32 MFMA C/D frag
typedef __attribute__((ext_vector_type(4))) unsigned short us4;

__device__ inline ushort_t f2bf(float f) {   // RNE fp32 -> bf16
    unsigned u = __float_as_uint(f);
    u += 0x7fffu + ((u >> 16) & 1u);
    return (ushort_t)(u >> 16);
}
__device__ inline float bf2f(ushort_t h) { return __uint_as_float(((unsigned)h) << 16); }

__device__ inline void upadd(float* acc, uint4 A) {   // accumulate 8 bf16 of a 16B chunk
    acc[0] += __uint_as_float(A.x << 16);
    acc[1] += __uint_as_float(A.x & 0xffff0000u);
    acc[2] += __uint_as_float(A.y << 16);
    acc[3] += __uint_as_float(A.y & 0xffff0000u);
    acc[4] += __uint_as_float(A.z << 16);
    acc[5] += __uint_as_float(A.z & 0xffff0000u);
    acc[6] += __uint_as_float(A.w << 16);
    acc[7] += __uint_as_float(A.w & 0xffff0000u);
}

// ---------------- utility ----------------
// zero deg + flag, fill padded srcs with sentinel row N_NODES (zero row)
__global__ void zero_int_kernel(int* __restrict__ deg, int* __restrict__ flag,
                                int* __restrict__ srcs) {
    int i = blockIdx.x * 256 + threadIdx.x;
    if (i < N_NODES) deg[i] = 0;
    if (i == 0) *flag = 0;
    for (int k = i; k < SRCS_CAP; k += NB1 * 256) srcs[k] = N_NODES;
}

// int32 vs int64 edge_index layout probe (int64 little-endian => odd words all 0)
// PROVEN device-side probe — do NOT replace with in_sizes heuristics (r8/r9 aborts).
__global__ void detect_kernel(const int* __restrict__ w, int* __restrict__ flag) {
    int i = blockIdx.x * 256 + threadIdx.x;
    if (i < 8192) {
        if (w[2 * i + 1] != 0) atomicOr(flag, 1);
    }
}

// ---------------- CSR build (padded to multiple of 4 per node) ----------------
__global__ void hist_kernel(const int* __restrict__ w, const int* __restrict__ flag,
                            int* __restrict__ deg, int* __restrict__ rank) {
    int e = blockIdx.x * 256 + threadIdx.x;
    if (e >= N_EDGES) return;
    int is32 = *flag;
    int d = is32 ? w[N_EDGES + e] : w[2 * (N_EDGES + e)];
    rank[e] = atomicAdd(&deg[d], 1);
}

__global__ void scan1_kernel(const int* __restrict__ deg, int* __restrict__ off,
                             int* __restrict__ bsums) {
    __shared__ int s[256];
    int t = threadIdx.x;
    int i = blockIdx.x * 256 + t;
    int v = (i < N_NODES) ? ((deg[i] + 3) & ~3) : 0;   // padded degree (x4)
    s[t] = v;
    __syncthreads();
    for (int d = 1; d < 256; d <<= 1) {
        int w = (t >= d) ? s[t - d] : 0;
        __syncthreads();
        s[t] += w;
        __syncthreads();
    }
    if (i < N_NODES) off[i] = s[t] - v;
    if (t == 255) bsums[blockIdx.x] = s[255];
}

__global__ void scan2_kernel(int* __restrict__ bsums) {
    __shared__ int s[512];
    int t = threadIdx.x;
    int v = (t < NB1) ? bsums[t] : 0;
    s[t] = v;
    __syncthreads();
    for (int d = 1; d < 512; d <<= 1) {
        int w = (t >= d) ? s[t - d] : 0;
        __syncthreads();
        s[t] += w;
        __syncthreads();
    }
    if (t < NB1) bsums[t] = s[t] - v;
    if (t == NB1 - 1) bsums[NB1] = s[t];   // total padded edge count
}

__global__ void scan3_kernel(int* __restrict__ off, const int* __restrict__ bsums) {
    int i = blockIdx.x * 256 + threadIdx.x;
    if (i < N_NODES) off[i] = off[i] + bsums[blockIdx.x];
    if (i == 0) off[N_NODES] = bsums[NB1];
}

__global__ void scatter_kernel(const int* __restrict__ w, const int* __restrict__ flag,
                               const int* __restrict__ off, const int* __restrict__ rank,
                               int* __restrict__ srcs) {
    int e = blockIdx.x * 256 + threadIdx.x;
    if (e >= N_EDGES) return;
    int is32 = *flag;
    int s = is32 ? w[e] : w[2 * e];
    int d = is32 ? w[N_EDGES + e] : w[2 * (N_EDGES + e)];
    srcs[off[d] + rank[e]] = s;
}

// ---------------- dtype conversion + sentinel zero rows ----------------
// Wb1[n][k], k<64 -> W1rel, else W1root. Wb2[n][k], k<128 -> W2rel, else W2root.
__global__ void cvt_kernel(const float* __restrict__ x, ushort_t* __restrict__ xb,
                           const float* __restrict__ W1rel, const float* __restrict__ W1root,
                           const float* __restrict__ W2rel, const float* __restrict__ W2root,
                           ushort_t* __restrict__ Wb1, ushort_t* __restrict__ Wb2,
                           ushort_t* __restrict__ h1b) {
    int i = blockIdx.x * 256 + threadIdx.x; // quad id for x
    if (i < N_NODES * FIN / 4) {
        float4 v = ((const float4*)x)[i];
        us4 o = {f2bf(v.x), f2bf(v.y), f2bf(v.z), f2bf(v.w)};
        ((us4*)xb)[i] = o;
    }
    us4 z = {0, 0, 0, 0};
    if (i < 16) ((us4*)xb)[(size_t)N_NODES * 16 + i] = z;          // xb zero row
    if (i >= 16 && i < 48) ((us4*)h1b)[(size_t)N_NODES * 32 + (i - 16)] = z;  // h1b zero row
    if (i < HID * HID) {
        int n = i >> 7, k = i & 127;
        float v = (k < FIN) ? W1rel[n * FIN + k] : W1root[n * FIN + (k - FIN)];
        Wb1[i] = f2bf(v);
    }
    if (i < HID * 2 * HID) {
        int n = i >> 8, k = i & 255;
        float v = (k < HID) ? W2rel[n * HID + k] : W2root[n * HID + (k - HID)];
        Wb2[i] = f2bf(v);
    }
}

// ------- aggregation: one lane-group owns a full row; 4 edges in flight per node -------
// agg1: 8 nodes/wave x 8 lanes x 16B (full 128B row per group). Pad x4 => maskless.
// Per iteration: one int4 srcs load + 4 independent full-row gathers per node.
__global__ void agg1_kernel(const ushort_t* __restrict__ xb, const int* __restrict__ off,
                            const int* __restrict__ srcs, ushort_t* __restrict__ aggb) {
    int wid = (blockIdx.x * 256 + threadIdx.x) >> 6;   // wave id
    int lane = threadIdx.x & 63;
    int n = lane >> 3;                       // node sub 0..7
    unsigned c = lane & 7;                   // 16B chunk of the 128B row
    int node = wid * 8 + n;                  // exact: 100000 = 8 * 12500 waves
    int b = off[node], e = off[node + 1];
    float acc[8];
#pragma unroll
    for (int j = 0; j < 8; j++) acc[j] = 0.f;
    const uint4* rows = (const uint4*)xb;    // 8 chunks per row (incl. zero row N)
    for (int p = b; p < e; p += 4) {
        int4 s = *(const int4*)(srcs + p);   // p is 4-aligned (pad x4), srcs base 256B-aligned
        uint4 A = rows[(unsigned)s.x * 8u + c];
        uint4 B = rows[(unsigned)s.y * 8u + c];
        uint4 C = rows[(unsigned)s.z * 8u + c];
        uint4 D = rows[(unsigned)s.w * 8u + c];
        upadd(acc, A);
        upadd(acc, B);
        upadd(acc, C);
        upadd(acc, D);
    }
    uint4 o = {(unsigned)f2bf(acc[0]) | ((unsigned)f2bf(acc[1]) << 16),
               (unsigned)f2bf(acc[2]) | ((unsigned)f2bf(acc[3]) << 16),
               (unsigned)f2bf(acc[4]) | ((unsigned)f2bf(acc[5]) << 16),
               (unsigned)f2bf(acc[6]) | ((unsigned)f2bf(acc[7]) << 16)};
    ((uint4*)(aggb + (size_t)node * FIN))[c] = o;   // 8 lanes = full row
}

// agg2: 4 nodes/wave x 16 lanes x 16B (full 256B row per group). Pad x4 => maskless.
__global__ void agg2_kernel(const ushort_t* __restrict__ h1b, const int* __restrict__ off,
                            const int* __restrict__ srcs, ushort_t* __restrict__ aggb) {
    int wid = (blockIdx.x * 256 + threadIdx.x) >> 6;   // wave id
    int lane = threadIdx.x & 63;
    int n = lane >> 4;                       // node sub 0..3
    unsigned c = lane & 15;                  // 16B chunk of the 256B row
    int node = wid * 4 + n;                  // exact: 100000 = 4 * 25000 waves
    int b = off[node], e = off[node + 1];
    float acc[8];
#pragma unroll
    for (int j = 0; j < 8; j++) acc[j] = 0.f;
    const uint4* rows = (const uint4*)h1b;   // 16 chunks per row (incl. zero row N)
    for (int p = b; p < e; p += 4) {
        int4 s = *(const int4*)(srcs + p);   // p is 4-aligned (pad x4), srcs base 256B-aligned
        uint4 A = rows[(unsigned)s.x * 16u + c];
        uint4 B = rows[(unsigned)s.y * 16u + c];
        uint4 C = rows[(unsigned)s.z * 16u + c];
        uint4 D = rows[(unsigned)s.w * 16u + c];
        upadd(acc, A);
        upadd(acc, B);
        upadd(acc, C);
        upadd(acc, D);
    }
    uint4 o = {(unsigned)f2bf(acc[0]) | ((unsigned)f2bf(acc[1]) << 16),
               (unsigned)f2bf(acc[2]) | ((unsigned)f2bf(acc[3]) << 16),
               (unsigned)f2bf(acc[4]) | ((unsigned)f2bf(acc[5]) << 16),
               (unsigned)f2bf(acc[6]) | ((unsigned)f2bf(acc[7]) << 16)};
    ((uint4*)(aggb + (size_t)node * HID))[c] = o;   // 16 lanes = full row
}

// ------- MFMA GEMM layer 1: h1 = elu([agg1,x] @ Wb1^T + b1) -------
__global__ __launch_bounds__(256) void g1_kernel(
    const ushort_t* __restrict__ aggb, const ushort_t* __restrict__ xb,
    const ushort_t* __restrict__ Wb1, const float* __restrict__ b1,
    ushort_t* __restrict__ h1b) {
    __shared__ short8 wl8[2048];                 // 32 KB
    ushort_t* wl = (ushort_t*)wl8;
#pragma unroll
    for (int it = 0; it < 8; it++) {
        int q = it * 256 + threadIdx.x;
        int n = q >> 4, c = q & 15;
        short8 v = ((const short8*)Wb1)[q];
        *(short8*)(wl + n * HID + ((c ^ (n & 7)) << 3)) = v;
    }
    __syncthreads();

    int wave = threadIdx.x >> 6;
    int lane = threadIdx.x & 63;
    int nb = blockIdx.x * 128 + wave * 32;
    if (nb >= N_NODES) return;   // after the only barrier
    int half = lane >> 5, col = lane & 31;
    int nA = nb + col;
    if (nA >= N_NODES) nA = N_NODES - 1;

    short8 areg[8];
#pragma unroll
    for (int s = 0; s < 4; s++)
        areg[s] = *(const short8*)(aggb + (size_t)nA * FIN + s * 16 + half * 8);
#pragma unroll
    for (int s = 4; s < 8; s++)
        areg[s] = *(const short8*)(xb + (size_t)nA * FIN + (s - 4) * 16 + half * 8);

    fx16 acc[4];
#pragma unroll
    for (int jt = 0; jt < 4; jt++)
#pragma unroll
        for (int r = 0; r < 16; r++) acc[jt][r] = 0.f;

#pragma unroll
    for (int s = 0; s < 8; s++) {
        int c = 2 * s + half;
#pragma unroll
        for (int jt = 0; jt < 4; jt++) {
            int n = jt * 32 + col;
            short8 bq = *(const short8*)(wl + n * HID + ((c ^ (n & 7)) << 3));
            acc[jt] = __builtin_amdgcn_mfma_f32_32x32x16_bf16(areg[s], bq, acc[jt], 0, 0, 0);
        }
    }
#pragma unroll
    for (int jt = 0; jt < 4; jt++) {
        int j = jt * 32 + col;
        float bias = b1[j];
#pragma unroll
        for (int r = 0; r < 16; r++) {
            int node = nb + (r & 3) + 8 * (r >> 2) + 4 * half;
            if (node < N_NODES) {
                float v = acc[jt][r] + bias;
                v = v > 0.f ? v : __expf(v) - 1.f;
                h1b[(size_t)node * HID + j] = f2bf(v);
            }
        }
    }
}

// ------- MFMA GEMM layer 2 + MFMA MLP head -------
// LDS (43008 B, 3 blocks/CU):
//   [0..32768)      Wb2 K-half staging (32 KB, two passes), later t2 tile
//   [0..34816)      t2 tile [node][feature], stride 136 ushorts (16B-aligned rows)
//   [34816..43008)  Wfc1 padded 32x128 bf16, XOR-swizzled (disjoint from Wb2 region)
// Head: fc1 as 8 MFMAs on the tile, relu*Wfc2 per lane, 5-round shfl_xor butterfly.
__global__ __launch_bounds__(256) void g2h_kernel(
    const ushort_t* __restrict__ agg2b, const ushort_t* __restrict__ h1b,
    const ushort_t* __restrict__ Wb2, const float* __restrict__ b2,
    const float* __restrict__ Wfc1, const float* __restrict__ bfc1,
    const float* __restrict__ Wfc2, const float* __restrict__ bfc2,
    float* __restrict__ out) {
    __shared__ ushort_t smem[21504];             // 43008 B
    ushort_t* wl = smem;                         // 16384 ushorts (32 KB)
    ushort_t* wf = smem + 17408;                 // 4096 ushorts (8 KB)

    // stage Wfc1b once (region never touched by Wb2/tile)
#pragma unroll
    for (int it = 0; it < 16; it++) {
        int idx = it * 256 + threadIdx.x;        // 0..4095
        int m = idx >> 7, k = idx & 127;
        float v = (m < 20) ? Wfc1[m * HID + k] : 0.f;
        wf[m * 128 + (((k >> 3) ^ (m & 7)) << 3) + (k & 7)] = f2bf(v);
    }
    // stage Wb2 K-half 0 (cols 0..127)
#pragma unroll
    for (int it = 0; it < 8; it++) {
        int q = it * 256 + threadIdx.x;          // 0..2047
        int n = q >> 4, c = q & 15;
        short8 v = *(const short8*)(Wb2 + (size_t)n * 256 + c * 8);
        *(short8*)(wl + n * 128 + ((c ^ (n & 7)) << 3)) = v;
    }

    int wave = threadIdx.x >> 6;
    int lane = threadIdx.x & 63;
    int half = lane >> 5, col = lane & 31;
    int nb = blockIdx.x * 128 + wave * 32;       // tail waves keep running (barriers!)
    int nA = nb + col;
    if (nA >= N_NODES) nA = N_NODES - 1;

    short8 areg[16];
#pragma unroll
    for (int s = 0; s < 8; s++)
        areg[s] = *(const short8*)(agg2b + (size_t)nA * HID + s * 16 + half * 8);
#pragma unroll
    for (int s = 8; s < 16; s++)
        areg[s] = *(const short8*)(h1b + (size_t)nA * HID + (s - 8) * 16 + half * 8);

    fx16 acc[4];
#pragma unroll
    for (int jt = 0; jt < 4; jt++)
#pragma unroll
        for (int r = 0; r < 16; r++) acc[jt][r] = 0.f;

    __syncthreads();
#pragma unroll
    for (int s = 0; s < 8; s++) {                // K 0..127 (agg2 part)
        int c = 2 * s + half;
#pragma unroll
        for (int jt = 0; jt < 4; jt++) {
            int n = jt * 32 + col;
            short8 bq = *(const short8*)(wl + n * 128 + ((c ^ (n & 7)) << 3));
            acc[jt] = __builtin_amdgcn_mfma_f32_32x32x16_bf16(areg[s], bq, acc[jt], 0, 0, 0);
        }
    }
    __syncthreads();
    // stage Wb2 K-half 1 (cols 128..255)
#pragma unroll
    for (int it = 0; it < 8; it++) {
        int q = it * 256 + threadIdx.x;
        int n = q >> 4, c = q & 15;
        short8 v = *(const short8*)(Wb2 + (size_t)n * 256 + 128 + c * 8);
        *(short8*)(wl + n * 128 + ((c ^ (n & 7)) << 3)) = v;
    }
    __syncthreads();
#pragma unroll
    for (int s = 8; s < 16; s++) {               // K 128..255 (h1 part)
        int c = 2 * (s - 8) + half;
#pragma unroll
        for (int jt = 0; jt < 4; jt++) {
            int n = jt * 32 + col;
            short8 bq = *(const short8*)(wl + n * 128 + ((c ^ (n & 7)) << 3));
            acc[jt] = __builtin_amdgcn_mfma_f32_32x32x16_bf16(areg[s], bq, acc[jt], 0, 0, 0);
        }
    }
    __syncthreads();   // weights dead; reuse [0..34816) as t2 tile

    // t2 tile [node_local][feature], stride 136 ushorts
    ushort_t* tl = smem;
#pragma unroll
    for (int jt = 0; jt < 4; jt++) {
        int j = jt * 32 + col;
        float bias = b2[j];
#pragma unroll
        for (int r = 0; r < 16; r++) {
            int nl = wave * 32 + (r & 3) + 8 * (r >> 2) + 4 * half;
            tl[nl * 136 + j] = f2bf(acc[jt][r] + bias);
        }
    }
    __syncthreads();

    // fc1 as MFMA: A = t2 tile rows (node m = wave*32+col), B = Wfc1b (row col)
    short8 af[8];
#pragma unroll
    for (int s = 0; s < 8; s++)
        af[s] = *(const short8*)(tl + (wave * 32 + col) * 136 + s * 16 + half * 8);
    fx16 fa;
#pragma unroll
    for (int r = 0; r < 16; r++) fa[r] = 0.f;
#pragma unroll
    for (int s = 0; s < 8; s++) {
        int c = 2 * s + half;
        short8 bw = *(const short8*)(wf + col * 128 + ((c ^ (col & 7)) << 3));
        fa = __builtin_amdgcn_mfma_f32_32x32x16_bf16(af[s], bw, fa, 0, 0, 0);
    }
    // epilogue: relu(+bfc1) * Wfc2, butterfly-sum over the 32 output cols
    float biasv = (col < 20) ? bfc1[col] : 0.f;
    float w2v = (col < 20) ? Wfc2[col] : 0.f;
    float bz = bfc2[0];
    float red[16];
#pragma unroll
    for (int r = 0; r < 16; r++) {
        float v = fa[r] + biasv;
        v = (v > 0.f ? v : 0.f) * w2v;
        v += __shfl_xor(v, 1);
        v += __shfl_xor(v, 2);
        v += __shfl_xor(v, 4);
        v += __shfl_xor(v, 8);
        v += __shfl_xor(v, 16);
        red[r] = v;
    }
    if (col == 0) {
#pragma unroll
        for (int r = 0; r < 16; r++) {
            int nl = wave * 32 + (r & 3) + 8 * (r >> 2) + 4 * half;
            int ng = blockIdx.x * 128 + nl;
            if (ng < N_NODES) out[ng] = red[r] + bz;
        }
    }
}

// ---------------- launch ----------------
extern "C" void kernel_launch(void* const* d_in, const int* in_sizes, int n_in,
                              void* d_out, int out_size, void* d_ws, size_t ws_size,
                              hipStream_t stream) {
    const float* x = (const float*)d_in[0];
    const int* ei = (const int*)d_in[1];
    const float* W1rel = (const float*)d_in[2];
    const float* b1 = (const float*)d_in[3];
    const float* W1root = (const float*)d_in[4];
    const float* W2rel = (const float*)d_in[5];
    const float* b2 = (const float*)d_in[6];
    const float* W2root = (const float*)d_in[7];
    const float* Wfc1 = (const float*)d_in[8];
    const float* bfc1 = (const float*)d_in[9];
    const float* Wfc2 = (const float*)d_in[10];
    const float* bfc2 = (const float*)d_in[11];
    float* out = (float*)d_out;

    // all offsets rounded to 256B so every buffer alignment is by construction
    char* ws = (char*)d_ws;
    size_t o = 0;
    auto alloc = [&](size_t bytes) {
        char* p = ws + o;
        o += (bytes + 255) & ~(size_t)255;
        return p;
    };
    int* deg = (int*)alloc((size_t)N_NODES * 4);
    int* off = (int*)alloc((size_t)(N_NODES + 1) * 4);
    int* bsums = (int*)alloc(4096);
    int* flag = (int*)alloc(256);
    int* rank = (int*)alloc((size_t)N_EDGES * 4);                    // 3.2 MB
    int* srcs = (int*)alloc((size_t)SRCS_CAP * 4);                   // 4.4 MB
    ushort_t* xb = (ushort_t*)alloc((size_t)(N_NODES + 1) * FIN * 2);   // 12.8 MB (+zero row)
    ushort_t* agg1b = (ushort_t*)alloc((size_t)N_NODES * FIN * 2);      // 12.8 MB
    ushort_t* h1b = (ushort_t*)alloc((size_t)(N_NODES + 1) * HID * 2);  // 25.6 MB (+zero row)
    ushort_t* agg2b = (ushort_t*)alloc((size_t)N_NODES * HID * 2);      // 25.6 MB
    ushort_t* Wb1 = (ushort_t*)alloc((size_t)HID * HID * 2);            // 32 KB
    ushort_t* Wb2 = (ushort_t*)alloc((size_t)HID * 2 * HID * 2);        // 64 KB

    const int GW = (N_NODES + 127) / 128;  // 782 blocks: 4 waves x 32 nodes
    const int GA1 = N_NODES / 32;          // 3125 blocks: 4 waves x 8 nodes
    const int GA2 = N_NODES / 16;          // 6250 blocks: 4 waves x 4 nodes

    zero_int_kernel<<<NB1, 256, 0, stream>>>(deg, flag, srcs);
    detect_kernel<<<32, 256, 0, stream>>>(ei, flag);
    hist_kernel<<<(N_EDGES + 255) / 256, 256, 0, stream>>>(ei, flag, deg, rank);
    scan1_kernel<<<NB1, 256, 0, stream>>>(deg, off, bsums);
    scan2_kernel<<<1, 512, 0, stream>>>(bsums);
    scan3_kernel<<<NB1, 256, 0, stream>>>(off, bsums);
    scatter_kernel<<<(N_EDGES + 255) / 256, 256, 0, stream>>>(ei, flag, off, rank, srcs);
    cvt_kernel<<<(N_NODES * FIN / 4 + 255) / 256, 256, 0, stream>>>(
        x, xb, W1rel, W1root, W2rel, W2root, Wb1, Wb2, h1b);
    agg1_kernel<<<GA1, 256, 0, stream>>>(xb, off, srcs, agg1b);
    g1_kernel<<<GW, 256, 0, stream>>>(agg1b, xb, Wb1, b1, h1b);
    agg2_kernel<<<GA2, 256, 0, stream>>>(h1b, off, srcs, agg2b);
    g2h_kernel<<<GW, 256, 0, stream>>>(agg2b, h1b, Wb2, b2, Wfc1, bfc1, Wfc2, bfc2, out);
}